// Round 7
// baseline (254.455 us; speedup 1.0000x reference)
//
#include <hip/hip_runtime.h>
#include <hip/hip_bf16.h>
#include <stdint.h>

#define D_MODEL 4096
#define D_BASE  8192
#define K_SUB   1024
#define N_TOK   8192

typedef __attribute__((ext_vector_type(8))) short bf16x8;
typedef __attribute__((ext_vector_type(16))) float f32x16;

__device__ __forceinline__ unsigned short f2bf(float f) {
    union { float f; uint32_t u; } c; c.f = f;
    uint32_t u = c.u;
    uint32_t r = u + 0x7FFFu + ((u >> 16) & 1u);   // round-to-nearest-even
    return (unsigned short)(r >> 16);
}

__device__ __forceinline__ void gload_lds16(const void* g, void* l) {
    __builtin_amdgcn_global_load_lds(
        (__attribute__((address_space(1))) void*)g,
        (__attribute__((address_space(3))) void*)l, 16, 0, 0);
}

#define VMCNT(N) do { __builtin_amdgcn_sched_barrier(0); \
    asm volatile("s_waitcnt vmcnt(" #N ")" ::: "memory"); } while (0)
#define PHASE_MID() do { __builtin_amdgcn_sched_barrier(0); __builtin_amdgcn_s_barrier(); \
    asm volatile("s_waitcnt lgkmcnt(0)" ::: "memory"); __builtin_amdgcn_sched_barrier(0); } while (0)
#define PHASE_END() do { __builtin_amdgcn_sched_barrier(0); __builtin_amdgcn_s_barrier(); } while (0)

// ---------------- Fused prep: gather_u (256 blocks) | gather_v (1024) | convert_x (16384) ----
// gather_u: direct reg-gather, no LDS transpose. Block b covers k-rows [b*16, b*16+16).
//   Thread (nq=t>>2, kq=t&3): for 16 n-chunks, 4 column-gathered loads (4 consecutive
//   k-rows, same col) -> ushort4 store. Block working set = 16 rows x 32KB = 512KB,
//   L2-resident -> line-dedup across the 1024-n sweep.
// gather_v: 64x64 LDS transpose (proven R4 form).
// convert_x: f32->bf16 streaming, fills remaining BW while gathers run.
__global__ __launch_bounds__(256) void prep_fused(const float* __restrict__ x,
                                                  const int* __restrict__ idx,
                                                  const float* __restrict__ U,
                                                  const float* __restrict__ V,
                                                  unsigned short* __restrict__ xb,
                                                  unsigned short* __restrict__ Ut,
                                                  unsigned short* __restrict__ Vt) {
    __shared__ unsigned short tile[64][66];
    __shared__ int lidx[64];
    const int b = blockIdx.x;
    const int t = threadIdx.x;
    if (b < 256) {
        // ---- gather_u ----
        const int nq = t >> 2, kq = t & 3;
        const int k0 = b * 16 + kq * 4;
        #pragma unroll
        for (int c = 0; c < 16; ++c) {
            int n = nq + 64 * c;
            int col = idx[n];
            const float* Ucol = U + (size_t)k0 * D_BASE + col;
            ushort4 o;
            o.x = f2bf(Ucol[0]);
            o.y = f2bf(Ucol[(size_t)D_BASE]);
            o.z = f2bf(Ucol[(size_t)2 * D_BASE]);
            o.w = f2bf(Ucol[(size_t)3 * D_BASE]);
            *(ushort4*)(Ut + (size_t)n * D_MODEL + k0) = o;
        }
    } else if (b < 256 + 1024) {
        // ---- gather_v ----
        const int bx = b - 256;
        const int n0 = (bx & 15) * 64;
        const int d0 = (bx >> 4) * 64;
        if (t < 64) lidx[t] = idx[n0 + t];
        __syncthreads();
        const int c = t & 63, r4 = t >> 6;
        #pragma unroll
        for (int p = 0; p < 16; ++p) {
            int nr = p * 4 + r4;
            tile[nr][c] = f2bf(V[(size_t)lidx[nr] * D_MODEL + d0 + c]);
        }
        __syncthreads();
        #pragma unroll
        for (int p = 0; p < 16; ++p) {
            int dr = p * 4 + r4;
            Vt[(size_t)(d0 + dr) * K_SUB + n0 + c] = tile[c][dr];
        }
    } else {
        // ---- convert_x ----
        const int cb = b - 1280;
        int e = cb * 256 + t;
        const float4* p = (const float4*)x + (size_t)e * 2;
        float4 a = p[0], q = p[1];
        ushort4 lo, hi;
        lo.x = f2bf(a.x); lo.y = f2bf(a.y); lo.z = f2bf(a.z); lo.w = f2bf(a.w);
        hi.x = f2bf(q.x); hi.y = f2bf(q.y); hi.z = f2bf(q.z); hi.w = f2bf(q.w);
        *(ushort4*)(xb + (size_t)e * 8) = lo;
        *(ushort4*)(xb + (size_t)e * 8 + 4) = hi;
    }
}

// ---------------- GEMM1: P = silu(xb @ Usub), M=8192 N=1024 K=4096 ----------------
// BM=256 BN=128 BK=64, 8 waves 4M x 2N -> wave 64x64. 32x32x16 MFMA:
// 2 m-frags x 2 n-frags x 4 k-slices = 16 MFMA/tile/wave, same 16 ds_read_b128.
// Schedule/ledger identical to R6 (proven): 4 phases / 2 K-tiles; stages
// p0:{A1[T+1],B[T+1]} p1:{A0[T+2]} p2:{A1[T+2],B[T+2]} p3:{A0[T+3]};
// waits end-p1 vmcnt(2) (or 0 at tail), end-p3 vmcnt(2).
__global__ __launch_bounds__(512, 2)
void gemm1_8p(const unsigned short* __restrict__ A, const unsigned short* __restrict__ Bt,
              unsigned short* __restrict__ C) {
    constexpr int K = D_MODEL, N = K_SUB, NT = K / 64;   // NT=64
    __shared__ __align__(16) unsigned short lds[49152];  // 96 KB

    const int t = threadIdx.x, lane = t & 63, w = t >> 6;
    const int wm = w >> 1, wn = w & 1;
    const int l31 = lane & 31, lh = lane >> 5;

    const int f = blockIdx.x;
    const int g = (f & 7) * 32 + (f >> 3);
    const int m0 = (g >> 3) * 256, n0 = (g & 7) * 128;

    const int srow = lane >> 3;
    const int scol = ((lane & 7) ^ srow) * 8;

    auto stage_A = [&](int kt, int half) {
        const unsigned short* src = A + (size_t)(m0 + half * 128) * K + kt * 64;
        unsigned short* dst = &lds[(kt & 1) * 24576 + half * 8192];
        #pragma unroll
        for (int i = 0; i < 2; ++i) {
            int c2 = i * 8 + w;
            gload_lds16(src + (size_t)(c2 * 8 + srow) * K + scol, dst + c2 * 512);
        }
    };
    auto stage_B = [&](int kt) {
        const unsigned short* src = Bt + (size_t)n0 * K + kt * 64;
        unsigned short* dst = &lds[(kt & 1) * 24576 + 16384];
        #pragma unroll
        for (int i = 0; i < 2; ++i) {
            int c2 = i * 8 + w;
            gload_lds16(src + (size_t)(c2 * 8 + srow) * K + scol, dst + c2 * 512);
        }
    };
    auto read_A = [&](int kt, bf16x8 (&af)[2][4]) {       // [mf][ks16]
        const unsigned short* base = &lds[(kt & 1) * 24576 + (wm >> 1) * 8192];
        #pragma unroll
        for (int mf = 0; mf < 2; ++mf) {
            int rw = (wm & 1) * 64 + mf * 32 + l31;
            #pragma unroll
            for (int ks = 0; ks < 4; ++ks) {
                int gg = ks * 2 + lh;
                af[mf][ks] = *(const bf16x8*)(base + rw * 64 + ((gg ^ (rw & 7)) * 8));
            }
        }
    };
    auto read_B1 = [&](int kt, int nf, bf16x8 (&bfr)[4]) {
        const unsigned short* base = &lds[(kt & 1) * 24576 + 16384];
        int rw = wn * 64 + nf * 32 + l31;
        #pragma unroll
        for (int ks = 0; ks < 4; ++ks) {
            int gg = ks * 2 + lh;
            bfr[ks] = *(const bf16x8*)(base + rw * 64 + ((gg ^ (rw & 7)) * 8));
        }
    };

    f32x16 acc[2][2] = {};   // [mf][nf]

    stage_A(0, 0); stage_A(0, 1); stage_B(0); stage_A(1, 0);
    VMCNT(2);
    __builtin_amdgcn_s_barrier();
    __builtin_amdgcn_sched_barrier(0);

    for (int kt = 0; kt < NT; kt += 2) {
        const bool more = (kt + 2 < NT);
        {   // p0: tile kt, n-frag 0
            bf16x8 af[2][4], bfr[4];
            read_A(kt, af); read_B1(kt, 0, bfr);
            stage_A(kt + 1, 1); stage_B(kt + 1);
            PHASE_MID();
            __builtin_amdgcn_s_setprio(1);
            #pragma unroll
            for (int mf = 0; mf < 2; ++mf)
                #pragma unroll
                for (int ks = 0; ks < 4; ++ks)
                    acc[mf][0] = __builtin_amdgcn_mfma_f32_32x32x16_bf16(
                        af[mf][ks], bfr[ks], acc[mf][0], 0, 0, 0);
            __builtin_amdgcn_s_setprio(0);
            PHASE_END();
            // p1: tile kt, n-frag 1 (af reused)
            bf16x8 bfr2[4];
            read_B1(kt, 1, bfr2);
            if (more) stage_A(kt + 2, 0);
            PHASE_MID();
            __builtin_amdgcn_s_setprio(1);
            #pragma unroll
            for (int mf = 0; mf < 2; ++mf)
                #pragma unroll
                for (int ks = 0; ks < 4; ++ks)
                    acc[mf][1] = __builtin_amdgcn_mfma_f32_32x32x16_bf16(
                        af[mf][ks], bfr2[ks], acc[mf][1], 0, 0, 0);
            __builtin_amdgcn_s_setprio(0);
            if (more) { VMCNT(2); } else { VMCNT(0); }
            PHASE_END();
        }
        {   // p2: tile kt+1, n-frag 0
            bf16x8 af[2][4], bfr[4];
            read_A(kt + 1, af); read_B1(kt + 1, 0, bfr);
            if (more) { stage_A(kt + 2, 1); stage_B(kt + 2); }
            PHASE_MID();
            __builtin_amdgcn_s_setprio(1);
            #pragma unroll
            for (int mf = 0; mf < 2; ++mf)
                #pragma unroll
                for (int ks = 0; ks < 4; ++ks)
                    acc[mf][0] = __builtin_amdgcn_mfma_f32_32x32x16_bf16(
                        af[mf][ks], bfr[ks], acc[mf][0], 0, 0, 0);
            __builtin_amdgcn_s_setprio(0);
            PHASE_END();
            // p3: tile kt+1, n-frag 1
            bf16x8 bfr2[4];
            read_B1(kt + 1, 1, bfr2);
            if (more) stage_A(kt + 3, 0);
            PHASE_MID();
            __builtin_amdgcn_s_setprio(1);
            #pragma unroll
            for (int mf = 0; mf < 2; ++mf)
                #pragma unroll
                for (int ks = 0; ks < 4; ++ks)
                    acc[mf][1] = __builtin_amdgcn_mfma_f32_32x32x16_bf16(
                        af[mf][ks], bfr2[ks], acc[mf][1], 0, 0, 0);
            __builtin_amdgcn_s_setprio(0);
            if (more) VMCNT(2);
            PHASE_END();
        }
    }

    // epilogue: 32x32 C layout: col=lane&31, row=(j&3)+8*(j>>2)+4*(lane>>5)
    #pragma unroll
    for (int mf = 0; mf < 2; ++mf)
        #pragma unroll
        for (int nf = 0; nf < 2; ++nf)
            #pragma unroll
            for (int j = 0; j < 16; ++j) {
                int row = m0 + wm * 64 + mf * 32 + (j & 3) + 8 * (j >> 2) + 4 * lh;
                int col = n0 + wn * 64 + nf * 32 + l31;
                float v = acc[mf][nf][j];
                v = v / (1.0f + __expf(-v));
                C[(size_t)row * N + col] = f2bf(v);
            }
}

// ---------------- GEMM2: out = P @ Vsub, M=8192 N=4096 K=1024 ----------------
// 256x256, 8 waves 2M x 4N -> wave 128x64. 32x32x16 MFMA: per quadrant (mh,nh):
// 2 m-frags x 1 n-frag x 4 k = 8 MFMA. Schedule/ledger identical to R4-proven.
__global__ __launch_bounds__(512, 2)
void gemm2_8p(const unsigned short* __restrict__ A, const unsigned short* __restrict__ Bt,
              float* __restrict__ C) {
    constexpr int K = K_SUB, N = D_MODEL, NT = K / 64;   // NT=16
    constexpr int BUFSZ = 32768;
    __shared__ __align__(16) unsigned short lds[2 * BUFSZ];   // 128 KB

    const int t = threadIdx.x, lane = t & 63, w = t >> 6;
    const int wr = w >> 2, wc = w & 3;
    const int l31 = lane & 31, lh = lane >> 5;

    const int f = blockIdx.x;
    const int g = (f & 7) * 64 + (f >> 3);
    const int m0 = (g >> 4) * 256, n0 = (g & 15) * 256;

    const int srow = lane >> 3;
    const int scol = ((lane & 7) ^ srow) * 8;

    auto stage_A = [&](int kt, int mh) {
        const unsigned short* src = A + (size_t)(m0 + mh * 128) * K + kt * 64;
        unsigned short* dst = &lds[(kt & 1) * BUFSZ + mh * 8192];
        #pragma unroll
        for (int i = 0; i < 2; ++i) {
            int c2 = i * 8 + w;
            gload_lds16(src + (size_t)(c2 * 8 + srow) * K + scol, dst + c2 * 512);
        }
    };
    auto stage_B = [&](int kt, int nh) {
        const unsigned short* src = Bt + (size_t)(n0 + nh * 128) * K + kt * 64;
        unsigned short* dst = &lds[(kt & 1) * BUFSZ + 16384 + nh * 8192];
        #pragma unroll
        for (int i = 0; i < 2; ++i) {
            int c2 = i * 8 + w;
            gload_lds16(src + (size_t)(c2 * 8 + srow) * K + scol, dst + c2 * 512);
        }
    };
    auto read_A = [&](int kt, int mh, bf16x8 (&af)[2][4]) {
        const unsigned short* base = &lds[(kt & 1) * BUFSZ + mh * 8192];
        #pragma unroll
        for (int mf = 0; mf < 2; ++mf) {
            int rw = wr * 64 + mf * 32 + l31;
            #pragma unroll
            for (int ks = 0; ks < 4; ++ks) {
                int gg = ks * 2 + lh;
                af[mf][ks] = *(const bf16x8*)(base + rw * 64 + ((gg ^ (rw & 7)) * 8));
            }
        }
    };
    auto read_B = [&](int kt, int nh, bf16x8 (&bfr)[4]) {
        const unsigned short* base = &lds[(kt & 1) * BUFSZ + 16384 + nh * 8192];
        int rw = wc * 32 + l31;
        #pragma unroll
        for (int ks = 0; ks < 4; ++ks) {
            int gg = ks * 2 + lh;
            bfr[ks] = *(const bf16x8*)(base + rw * 64 + ((gg ^ (rw & 7)) * 8));
        }
    };

    f32x16 acc00[2] = {}, acc01[2] = {}, acc10[2] = {}, acc11[2] = {};

    stage_A(0, 0); stage_B(0, 0); stage_B(0, 1); stage_A(0, 1);
    stage_A(1, 0); stage_B(1, 1); stage_A(1, 1);
    VMCNT(6);
    __builtin_amdgcn_s_barrier();
    __builtin_amdgcn_sched_barrier(0);

    for (int kt = 0; kt < NT; ++kt) {
        bf16x8 af[2][4], bf0[4], bf1[4];
        {   // p0: quadrant (0,0)
            read_A(kt, 0, af); read_B(kt, 0, bf0);
            if (kt + 1 < NT) stage_B(kt + 1, 0);
            PHASE_MID();
            __builtin_amdgcn_s_setprio(1);
            #pragma unroll
            for (int mf = 0; mf < 2; ++mf)
                #pragma unroll
                for (int ks = 0; ks < 4; ++ks)
                    acc00[mf] = __builtin_amdgcn_mfma_f32_32x32x16_bf16(
                        af[mf][ks], bf0[ks], acc00[mf], 0, 0, 0);
            __builtin_amdgcn_s_setprio(0);
            PHASE_END();
        }
        {   // p1: quadrant (0,1)
            read_B(kt, 1, bf1);
            if (kt + 2 < NT) stage_A(kt + 2, 0);
            PHASE_MID();
            __builtin_amdgcn_s_setprio(1);
            #pragma unroll
            for (int mf = 0; mf < 2; ++mf)
                #pragma unroll
                for (int ks = 0; ks < 4; ++ks)
                    acc01[mf] = __builtin_amdgcn_mfma_f32_32x32x16_bf16(
                        af[mf][ks], bf1[ks], acc01[mf], 0, 0, 0);
            __builtin_amdgcn_s_setprio(0);
            PHASE_END();
        }
        {   // p2: quadrant (1,0)
            read_A(kt, 1, af);
            if (kt + 2 < NT) stage_B(kt + 2, 1);
            PHASE_MID();
            __builtin_amdgcn_s_setprio(1);
            #pragma unroll
            for (int mf = 0; mf < 2; ++mf)
                #pragma unroll
                for (int ks = 0; ks < 4; ++ks)
                    acc10[mf] = __builtin_amdgcn_mfma_f32_32x32x16_bf16(
                        af[mf][ks], bf0[ks], acc10[mf], 0, 0, 0);
            __builtin_amdgcn_s_setprio(0);
            PHASE_END();
        }
        {   // p3: quadrant (1,1)
            if (kt + 2 < NT) stage_A(kt + 2, 1);
            PHASE_MID();
            __builtin_amdgcn_s_setprio(1);
            #pragma unroll
            for (int mf = 0; mf < 2; ++mf)
                #pragma unroll
                for (int ks = 0; ks < 4; ++ks)
                    acc11[mf] = __builtin_amdgcn_mfma_f32_32x32x16_bf16(
                        af[mf][ks], bf1[ks], acc11[mf], 0, 0, 0);
            __builtin_amdgcn_s_setprio(0);
            __builtin_amdgcn_sched_barrier(0);
            if (kt < NT - 2) { VMCNT(6); }
            else if (kt == NT - 2) { VMCNT(0); }
            PHASE_END();
        }
    }

    #pragma unroll
    for (int mf = 0; mf < 2; ++mf)
        #pragma unroll
        for (int j = 0; j < 16; ++j) {
            int rbase = (j & 3) + 8 * (j >> 2) + 4 * lh + mf * 32 + wr * 64;
            int cbase = wc * 32 + l31;
            C[(size_t)(m0 + rbase) * N + (n0 + cbase)]             = acc00[mf][j];
            C[(size_t)(m0 + rbase) * N + (n0 + 128 + cbase)]       = acc01[mf][j];
            C[(size_t)(m0 + 128 + rbase) * N + (n0 + cbase)]       = acc10[mf][j];
            C[(size_t)(m0 + 128 + rbase) * N + (n0 + 128 + cbase)] = acc11[mf][j];
        }
}

extern "C" void kernel_launch(void* const* d_in, const int* in_sizes, int n_in,
                              void* d_out, int out_size, void* d_ws, size_t ws_size,
                              hipStream_t stream) {
    const float* x   = (const float*)d_in[0];
    const int*   idx = (const int*)d_in[1];
    const float* U   = (const float*)d_in[2];
    const float* V   = (const float*)d_in[3];
    float* out = (float*)d_out;

    unsigned short* Ut = (unsigned short*)d_ws;                 // [K_SUB][D_MODEL] bf16
    unsigned short* Vt = Ut + (size_t)K_SUB * D_MODEL;          // [D_MODEL][K_SUB] bf16
    unsigned short* P  = Vt + (size_t)K_SUB * D_MODEL;          // [N_TOK][K_SUB]  bf16
    unsigned short* xb = (unsigned short*)d_out;                // [N_TOK][D_MODEL] bf16 (temp)

    prep_fused<<<256 + 1024 + 16384, 256, 0, stream>>>(x, idx, U, V, xb, Ut, Vt);
    gemm1_8p<<<256, 512, 0, stream>>>(xb, Ut, P);
    gemm2_8p<<<512, 512, 0, stream>>>(P, Vt, out);
}